// Round 7
// baseline (538.231 us; speedup 1.0000x reference)
//
#include <hip/hip_runtime.h>
#include <stdint.h>

// Problem dims fixed by the reference: C=500, G=200, F=500, K=10, NF=5e6.
#define C_   500
#define G_   200
#define F_   500
#define K_   10
#define CG_  (C_ * G_)           // 100000
#define NW   (CG_ * F_ / 8)      // 6,250,000 u32 words of 4-bit counters (25 MB)
#define GRID_S 1024              // 4 blocks/CU exactly
#define TPB_S  512
#define CHUNK_MAX 5120           // = FPT2*TPB_S*2 capacity
#define FPT2 5                   // int2 pairs per thread (5*512*2=5120 >= 4884)
#define LN2F 0.69314718f

// R7 design (from R6 counters: latency-bound, not BW/issue-bound):
// the frag16 roundtrip + both LDS histogram machines existed only to give
// each fragment its rank o within its (cg,f) cell. A GLOBAL 4-bit counter
// table (25 MB, L2/L3 resident) returns o directly from one atomicAdd.
// out[cg] = sum_frag (u[pair,f] - ln(o+1)) - E[pair]   (lgamma telescoping,
// numerically validated by R6: absmax stayed 4.0). Poisson(0.1) cell counts
// -> nibble overflow probability ~0.
// Kernels: setup (zero nib+acc, build u_tab+E), scatter (5M frags, 3 mem
// ops each, 32 waves/CU TLP hides atomic latency), epilogue (out=acc-E).

__global__ __launch_bounds__(TPB_S) void setup_kernel(
        const float* __restrict__ bc,
        const float* __restrict__ bw,
        const int* __restrict__ genes_oi,
        const float* __restrict__ dw,
        const float* __restrict__ cm,
        uint32_t* __restrict__ nib,
        float* __restrict__ acc,
        float* __restrict__ u_tab,
        float* __restrict__ E) {
    __shared__ float psum[2];
    int tid = threadIdx.x, blk = blockIdx.x;
    if (tid < 2) psum[tid] = 0.0f;
    __syncthreads();

    // Zero the nibble table (25 MB) + accumulator (400 KB), grid-stride uint4.
    uint4 z = make_uint4(0u, 0u, 0u, 0u);
    uint4* n4 = (uint4*)nib;
    for (int i = blk * TPB_S + tid; i < NW / 4; i += GRID_S * TPB_S) n4[i] = z;
    uint4* a4 = (uint4*)acc;
    for (int i = blk * TPB_S + tid; i < CG_ / 4; i += GRID_S * TPB_S) a4[i] = z;

    // u_tab + E: 2 (k,g) pairs per block (blocks 0..999), 256 threads/pair.
    if (blk < K_ * G_ / 2) {
        int p = blk * 2 + (tid >> 8);
        int sub = tid & 255;
        int k = p / G_;
        int g = p - k * G_;
        float dwk = dw[k];
        float cmk = cm[k];
        const float* bcg = bc + (size_t)g * F_;
        const float* bwg = bw + (size_t)genes_oi[g] * F_;
        float* urow = u_tab + (size_t)p * F_;
        float u0 = dwk * bcg[sub] + bwg[sub] + cmk;
        urow[sub] = u0;
        float s = __expf(u0);
        int f1 = sub + 256;
        if (f1 < F_) {
            float u1 = dwk * bcg[f1] + bwg[f1] + cmk;
            urow[f1] = u1;
            s += __expf(u1);
        }
#pragma unroll
        for (int off = 32; off > 0; off >>= 1) s += __shfl_down(s, off);
        if ((tid & 63) == 0) atomicAdd(&psum[tid >> 8], s);
        __syncthreads();                  // block-uniform condition: legal
        if ((tid & 255) == 0) E[p] = psum[tid >> 8];
    }
}

__device__ __forceinline__ void proc_frag(
        int cg, int f, const int* lab,
        const float* __restrict__ u_tab,
        uint32_t* __restrict__ nib,
        float* __restrict__ acc) {
    uint32_t c = (uint32_t)cg / 200u;               // magic-mul
    uint32_t g = (uint32_t)cg - c * 200u;
    uint32_t pair = (uint32_t)lab[c] * 200u + g;
    float uv = u_tab[pair * (uint32_t)F_ + (uint32_t)f];
    uint32_t cell = (uint32_t)cg * (uint32_t)F_ + (uint32_t)f;
    uint32_t sh = (cell & 7u) * 4u;
    uint32_t w = atomicAdd(&nib[cell >> 3], 1u << sh);
    uint32_t o = (w >> sh) & 0xFu;
    // branchless: log2(1)=0 exactly for the ~95% o==0 case
    float s = uv - __log2f((float)(o + 1u)) * LN2F;
    atomicAdd(&acc[cg], s);
}

__global__ __launch_bounds__(TPB_S) void scatter_kernel(
        const int* __restrict__ lci,
        const int* __restrict__ binix,
        const int* __restrict__ labels,
        const float* __restrict__ u_tab,
        uint32_t* __restrict__ nib,
        float* __restrict__ acc,
        int NF, int chunk) {
    __shared__ int lab[C_];
    int tid = threadIdx.x, blk = blockIdx.x;
    if (tid < C_) lab[tid] = labels[tid];
    __syncthreads();

    int s0 = blk * chunk;
    int s1 = min(s0 + chunk, NF);
    int nloc = s1 - s0;
    const int2* lci2 = (const int2*)(lci + s0);   // chunk even -> 8B aligned
    const int2* bin2 = (const int2*)(binix + s0);
#pragma unroll
    for (int u = 0; u < FPT2; ++u) {
        int pi = u * TPB_S + tid;
        int e0 = pi * 2;
        if (e0 + 1 < nloc) {
            int2 cg2 = lci2[pi];
            int2 f2  = bin2[pi];
            proc_frag(cg2.x, f2.x, lab, u_tab, nib, acc);
            proc_frag(cg2.y, f2.y, lab, u_tab, nib, acc);
        } else if (e0 < nloc) {                   // odd tail: single scalar
            proc_frag(lci[s0 + e0], binix[s0 + e0], lab, u_tab, nib, acc);
        }
    }
}

__global__ __launch_bounds__(TPB_S) void epilogue_kernel(
        const float* __restrict__ acc,
        const float* __restrict__ E,
        const int* __restrict__ labels,
        float* __restrict__ out) {
    int i = blockIdx.x * TPB_S + threadIdx.x;
    if (i < CG_) {
        uint32_t c = (uint32_t)i / 200u;
        uint32_t g = (uint32_t)i - c * 200u;
        out[i] = acc[i] - E[(uint32_t)labels[c] * 200u + g];
    }
}

extern "C" void kernel_launch(void* const* d_in, const int* in_sizes, int n_in,
                              void* d_out, int out_size, void* d_ws, size_t ws_size,
                              hipStream_t stream) {
    const float* bc     = (const float*)d_in[0];
    const float* bw     = (const float*)d_in[1];
    const float* dw     = (const float*)d_in[2];
    const float* cm     = (const float*)d_in[3];
    const int* genes_oi = (const int*)d_in[4];
    const int* labels   = (const int*)d_in[5];
    const int* lci      = (const int*)d_in[6];
    const int* binix    = (const int*)d_in[7];
    float* out = (float*)d_out;

    const int NF = in_sizes[6];
    int chunk = (NF + GRID_S - 1) / GRID_S;   // 4883 for NF=5e6
    chunk = (chunk + 1) & ~1;                 // force even (int2 alignment)
    if (chunk > CHUNK_MAX) chunk = CHUNK_MAX;

    // ws: [nib 25MB][u_tab 4MB][acc 400KB][E 8KB]
    char* ws = (char*)d_ws;
    size_t off_utab = ((size_t)NW * 4 + 255) & ~(size_t)255;
    size_t off_acc  = (off_utab + (size_t)K_ * G_ * F_ * 4 + 255) & ~(size_t)255;
    size_t off_E    = (off_acc + (size_t)CG_ * 4 + 255) & ~(size_t)255;

    uint32_t* nib   = (uint32_t*)ws;
    float*    u_tab = (float*)(ws + off_utab);
    float*    acc   = (float*)(ws + off_acc);
    float*    E     = (float*)(ws + off_E);

    setup_kernel<<<GRID_S, TPB_S, 0, stream>>>(
        bc, bw, genes_oi, dw, cm, nib, acc, u_tab, E);

    scatter_kernel<<<GRID_S, TPB_S, 0, stream>>>(
        lci, binix, labels, u_tab, nib, acc, NF, chunk);

    epilogue_kernel<<<(CG_ + TPB_S - 1) / TPB_S, TPB_S, 0, stream>>>(
        acc, E, labels, out);
}

// Round 8
// 126.009 us; speedup vs baseline: 4.2714x; 4.2714x over previous
//
#include <hip/hip_runtime.h>
#include <stdint.h>

// Problem dims fixed by the reference: C=500, G=200, F=500, K=10, NF=5e6.
#define C_   500
#define G_   200
#define F_   500
#define K_   10
#define CG_  (C_ * G_)          // 100000
#define CGPB 128                // R8: power-of-2 -> b = cg>>7, no magic div.
                                // pack (cg&127)<<9 | f: max 65523 < 2^16 OK
#define NBUCK ((CG_ + CGPB - 1) / CGPB)  // 782
#define WPRW 64                 // count-words per cg row (512 nibbles)
#define NCW  (CGPB * WPRW)      // 8192 words = 32 KB (/4 exact)
#define TPB_P 1024
#define GRID_P 512              // = NBLK; 2 blocks/CU
#define NBLK 512
#define TPB_B 512
#define CHUNK_MAX 10240         // >= ceil(NF/GRID_P) = 9766 (even)
#define FPT2 (CHUNK_MAX / TPB_P / 2) // 5 int2 pairs per thread
#define SLOT 32                 // 64B = 4 aligned sectors; lambda=12.5 ->
                                // P(n>32) ~ 1e-7/seg, ovf path covers it
#define OVF_CAP 32              // per-block overflow list capacity
#define LN2F 0.69314718f

// lgamma(n+1) for n = 0..15
__constant__ float LGF[16] = {
    0.0f, 0.0f, 0.69314718f, 1.79175947f, 3.17805383f, 4.78749174f,
    6.57925121f, 8.52516136f, 10.60460290f, 12.80182748f, 15.10441257f,
    17.50230785f, 19.98721450f, 22.55216385f, 25.19122118f, 27.89927138f
};

// R5 single-pass partition + R8 instruction diet (partition is issue-bound:
// ~12 inst/frag x 8 waves/SIMD ~= measured ~40us). CGPB=128 kills the magic
// div; u=0..3 pair iterations are provably in-bounds (nloc >= 9574 for all
// blocks at NF=5e6), only the last iteration keeps the tail check.
// NOTE (R12): LDS slot array IS the reorder — grouped 64B-sector writes.
// NOTE (R2): segment-per-thread scattered stores regressed; adjacent lanes
// here write adjacent quads. NOTE (R4): no cooperative launch, LDS < 64KB.
// NOTE (R7): never random global atomics across a >L2 table (312MB
// writeback storm, 450us).
__global__ __launch_bounds__(TPB_P) void partition_kernel(
        const int* __restrict__ lci,
        const int* __restrict__ binix,
        const float* __restrict__ bc,
        const float* __restrict__ bw,
        const int* __restrict__ genes_oi,
        const float* __restrict__ dw,
        const float* __restrict__ cm,
        uint16_t* __restrict__ frag16,
        uint16_t* __restrict__ cnt16,
        uint32_t* __restrict__ ovfn,
        uint32_t* __restrict__ ovfe,
        float* __restrict__ u_tab,
        float* __restrict__ E,
        int NF, int chunk) {
    __shared__ uint16_t smem16[NBUCK * SLOT];  // 50 KB slot staging
    __shared__ uint32_t hist[NBUCK];           // 3.1 KB
    __shared__ float    psum[4];
    __shared__ uint32_t ovf_lds[OVF_CAP];
    __shared__ uint32_t oc;
    int tid = threadIdx.x;
    int blk = blockIdx.x;
    int s0 = blk * chunk;
    int s1 = min(s0 + chunk, NF);
    int nloc = s1 - s0;

    if (tid < NBUCK) hist[tid] = 0;
    if (tid < 4) psum[tid] = 0.0f;
    if (tid == 0) oc = 0u;
    __syncthreads();                           // barrier A

    // --- utab prologue: 4 pairs per block, 256 threads per pair ---
    {
        int p = blk * 4 + (tid >> 8);
        if (p < K_ * G_) {
            int sub = tid & 255;
            int k = p / G_;
            int g = p - k * G_;
            float dwk = dw[k];
            float cmk = cm[k];
            const float* bcg = bc + (size_t)g * F_;
            const float* bwg = bw + (size_t)genes_oi[g] * F_;
            float* urow = u_tab + (size_t)p * F_;
            float u0 = dwk * bcg[sub] + bwg[sub] + cmk;
            urow[sub] = u0;
            float s = __expf(u0);
            int f1 = sub + 256;
            if (f1 < F_) {
                float u1 = dwk * bcg[f1] + bwg[f1] + cmk;
                urow[f1] = u1;
                s += __expf(u1);
            }
#pragma unroll
            for (int off = 32; off > 0; off >>= 1) s += __shfl_down(s, off);
            if ((tid & 63) == 0) atomicAdd(&psum[tid >> 8], s);
        }
    }

    // --- Phase 1: int2 loads; rank atomic -> direct LDS slot write ---
    const int2* lci2 = (const int2*)(lci + s0);   // chunk even -> 8B aligned
    const int2* bin2 = (const int2*)(binix + s0);

    auto frag = [&](uint32_t cg, uint32_t f) {
        uint32_t b  = cg >> 7;                     // CGPB = 128
        uint32_t lp = ((cg & 127u) << 9) | f;
        uint32_t r  = atomicAdd(&hist[b], 1u);
        if (r < SLOT) smem16[b * SLOT + r] = (uint16_t)lp;
        else {
            uint32_t o = atomicAdd(&oc, 1u);
            if (o < OVF_CAP) ovf_lds[o] = (b << 16) | lp;
        }
    };

    if (nloc >= 2 * 4 * TPB_P) {   // u=0..3 provably in-bounds (pi<4096)
#pragma unroll
        for (int u = 0; u < 4; ++u) {
            int pi = u * TPB_P + tid;
            int2 cg2 = lci2[pi];
            int2 f2  = bin2[pi];
            frag((uint32_t)cg2.x, (uint32_t)f2.x);
            frag((uint32_t)cg2.y, (uint32_t)f2.y);
        }
        {   // u = 4: tail-checked
            int pi = 4 * TPB_P + tid;
            int e0 = pi * 2;
            if (e0 + 1 < nloc) {
                int2 cg2 = lci2[pi];
                int2 f2  = bin2[pi];
                frag((uint32_t)cg2.x, (uint32_t)f2.x);
                frag((uint32_t)cg2.y, (uint32_t)f2.y);
            } else if (e0 < nloc) {
                frag((uint32_t)lci[s0 + e0], (uint32_t)binix[s0 + e0]);
            }
        }
    } else {                        // generic guarded path (defensive)
#pragma unroll
        for (int u = 0; u < FPT2; ++u) {
            int pi = u * TPB_P + tid;
            int e0 = pi * 2;
            if (e0 + 1 < nloc) {
                int2 cg2 = lci2[pi];
                int2 f2  = bin2[pi];
                frag((uint32_t)cg2.x, (uint32_t)f2.x);
                frag((uint32_t)cg2.y, (uint32_t)f2.y);
            } else if (e0 < nloc) {
                frag((uint32_t)lci[s0 + e0], (uint32_t)binix[s0 + e0]);
            }
        }
    }
    __syncthreads();                           // barrier B

    // E write, coalesced cnt16 write.
    if (tid < 4) {
        int p = blk * 4 + tid;
        if (p < K_ * G_) E[p] = psum[tid];
    }
    if (tid < NBUCK)
        cnt16[(size_t)blk * NBUCK + tid] = (uint16_t)min(hist[tid], (uint32_t)SLOT);

    // Write-out: uint4 copy of occupied quads (4 lanes per 64B segment).
    const uint4* s4 = (const uint4*)smem16;
    for (int i = tid; i < NBUCK * 4; i += TPB_P) {
        int seg = i >> 2;
        int q   = i & 3;
        uint32_t n = min(hist[seg], (uint32_t)SLOT);
        if ((uint32_t)(q * 8) < n) {
            uint4* dst = (uint4*)(frag16 + ((size_t)seg * NBLK + blk) * SLOT);
            dst[q] = s4[i];
        }
    }

    if (tid == 0) ovfn[blk] = min(oc, (uint32_t)OVF_CAP);
    if (tid < OVF_CAP && tid < oc) ovfe[blk * OVF_CAP + tid] = ovf_lds[tid];
}

// One block per bucket (782). Dense contiguous slot read (uint4: 4 quads per
// segment) -> nibble counts (LDS atomics) + rare overflow, then the proven
// wave-per-row scan (R3/R6 lessons: coalesced u-row float4 pairs beat
// per-fragment gathers; fused telescoping accumulate regressed). Last
// bucket (781) has only 32 valid rows -> cg < CG_ guards.
__global__ __launch_bounds__(TPB_B) void bucket_kernel(
        const uint16_t* __restrict__ frag16,
        const uint16_t* __restrict__ cnt16,
        const uint32_t* __restrict__ ovfn,
        const uint32_t* __restrict__ ovfe,
        const float* __restrict__ u_tab,
        const float* __restrict__ E,
        const int* __restrict__ labels,
        float* __restrict__ out) {
    __shared__ uint32_t cnt[NCW];             // 8192 words = 32 KB
    __shared__ uint16_t cnts[NBLK];           // 1 KB
    __shared__ int pairidx[CGPB];
    int b = blockIdx.x;
    int tid = threadIdx.x;

    uint4* c4 = (uint4*)cnt;
    for (int w = tid; w < NCW / 4; w += TPB_B) c4[w] = make_uint4(0u, 0u, 0u, 0u);
    if (tid < CGPB) {
        int cg = b * CGPB + tid;
        if (cg < CG_) {
            int c = cg / G_;
            int g = cg - c * G_;
            pairidx[tid] = labels[c] * G_ + g;
        } else {
            pairidx[tid] = 0;
        }
    }
    if (tid < NBLK) cnts[tid] = cnt16[(size_t)tid * NBUCK + b];
    __syncthreads();

    // Build: dense coalesced uint4 read of this bucket's slots.
    // Segment = SLOT(32) u16 = 64 B = 4 quads; quad q holds slots [8q,8q+8).
    const uint4* fb4 = (const uint4*)(frag16 + (size_t)b * NBLK * SLOT);
    for (int i = tid; i < NBLK * 4; i += TPB_B) {      // 4 iterations
        uint32_t blkq = (uint32_t)i >> 2;
        uint32_t q    = (uint32_t)i & 3u;
        int n  = (int)cnts[blkq];
        int j0 = (int)q * 8;
        if (j0 < n) {
            uint4 four = fb4[i];
            int m = n - j0;                            // valid u16s in quad
            uint32_t wq[4] = {four.x, four.y, four.z, four.w};
#pragma unroll
            for (int t = 0; t < 8; ++t) {
                if (t < m) {
                    uint32_t l = (wq[t >> 1] >> ((t & 1) * 16)) & 0xFFFFu;
                    atomicAdd(&cnt[l >> 3], 1u << ((l & 7u) * 4u));
                }
            }
        }
    }
    // Overflow entries (expected ~0 total).
    if (tid < NBLK) {
        uint32_t on = ovfn[tid];
        for (uint32_t q = 0; q < on; ++q) {
            uint32_t e = ovfe[tid * OVF_CAP + q];
            if ((e >> 16) == (uint32_t)b) {
                uint32_t l = e & 0xFFFFu;
                atomicAdd(&cnt[l >> 3], 1u << ((l & 7u) * 4u));
            }
        }
    }
    __syncthreads();

    // Scan: wave-per-row. Row r occupies words [r*64, r*64+63); only words
    // 0..62 can be nonzero (f < 500). Lane 62's float4 pair overreads 4
    // floats past the u-row end — zero nibbles there, u_tab is padded.
    int wave = tid >> 6, lane = tid & 63;
    for (int r = wave; r < CGPB; r += (TPB_B / 64)) {
        int cg = b * CGPB + r;
        if (cg >= CG_) break;                 // last bucket only
        float s = 0.0f;
        if (lane < 63) {
            uint32_t v = cnt[r * WPRW + lane];
            if (v) {
                const float4* up = (const float4*)(u_tab + (size_t)pairidx[r] * F_ + 8 * lane);
                float4 ua = up[0];
                float4 ub = up[1];
                s += (float)( v        & 0xFu) * ua.x
                   + (float)((v >> 4)  & 0xFu) * ua.y
                   + (float)((v >> 8)  & 0xFu) * ua.z
                   + (float)((v >> 12) & 0xFu) * ua.w
                   + (float)((v >> 16) & 0xFu) * ub.x
                   + (float)((v >> 20) & 0xFu) * ub.y
                   + (float)((v >> 24) & 0xFu) * ub.z
                   + (float)((v >> 28)       ) * ub.w;
                if (v & 0xEEEEEEEEu) {        // some nibble >= 2: rare
#pragma unroll
                    for (int q = 0; q < 8; ++q)
                        s -= LGF[(v >> (q * 4)) & 0xFu];
                }
            }
        }
#pragma unroll
        for (int off = 32; off > 0; off >>= 1) s += __shfl_down(s, off);
        if (lane == 0) out[cg] = s - E[pairidx[r]];
    }
}

extern "C" void kernel_launch(void* const* d_in, const int* in_sizes, int n_in,
                              void* d_out, int out_size, void* d_ws, size_t ws_size,
                              hipStream_t stream) {
    const float* bc     = (const float*)d_in[0];
    const float* bw     = (const float*)d_in[1];
    const float* dw     = (const float*)d_in[2];
    const float* cm     = (const float*)d_in[3];
    const int* genes_oi = (const int*)d_in[4];
    const int* labels   = (const int*)d_in[5];
    const int* lci      = (const int*)d_in[6];
    const int* binix    = (const int*)d_in[7];
    float* out = (float*)d_out;

    const int NF = in_sizes[6];
    int chunk = (NF + GRID_P - 1) / GRID_P;   // 9766 for NF=5e6
    chunk = (chunk + 1) & ~1;                 // force even (int2 alignment)
    if (chunk > CHUNK_MAX) chunk = CHUNK_MAX;

    // ws: [frag16][cnt16][ovfn][ovfe][u_tab(+pad)][E]
    char* ws = (char*)d_ws;
    size_t off_cnt16 = ((size_t)NBUCK * NBLK * SLOT * sizeof(uint16_t) + 255) & ~(size_t)255;
    size_t off_ovfn  = (off_cnt16 + (size_t)NBLK * NBUCK * sizeof(uint16_t) + 255) & ~(size_t)255;
    size_t off_ovfe  = (off_ovfn + NBLK * sizeof(uint32_t) + 255) & ~(size_t)255;
    size_t off_utab  = (off_ovfe + (size_t)NBLK * OVF_CAP * sizeof(uint32_t) + 255) & ~(size_t)255;
    size_t off_E     = (off_utab + ((size_t)K_ * G_ * F_ + 16) * sizeof(float) + 255) & ~(size_t)255;

    uint16_t* frag16 = (uint16_t*)ws;
    uint16_t* cnt16  = (uint16_t*)(ws + off_cnt16);
    uint32_t* ovfn   = (uint32_t*)(ws + off_ovfn);
    uint32_t* ovfe   = (uint32_t*)(ws + off_ovfe);
    float*    u_tab  = (float*)(ws + off_utab);
    float*    E      = (float*)(ws + off_E);

    partition_kernel<<<GRID_P, TPB_P, 0, stream>>>(
        lci, binix, bc, bw, genes_oi, dw, cm,
        frag16, cnt16, ovfn, ovfe, u_tab, E, NF, chunk);

    bucket_kernel<<<NBUCK, TPB_B, 0, stream>>>(
        frag16, cnt16, ovfn, ovfe, u_tab, E, labels, out);
}